// Round 8
// baseline (355.134 us; speedup 1.0000x reference)
//
#include <hip/hip_runtime.h>

// SOBA-Monarch, B*H=64 heads, S=4096, D=64, nb=bs=64, pad=0, 3 steps.
// Round 8 = R7 (packed-u32 intermediates, pad-72 LDS, direct stores) +
//   2 tiles/WG (grid 2048) with register prefetch of next tile's inputs
//   + R4 alpha/tau layouts (contiguous reads, scattered masked writes).
// Layouts: G [h][j][k][v] u32 | Hm,Y [h][k][j][v] u32 | M [h][j][v] u32
//          alpha [h][j][k] f32 | tau [h][k][j] f32

namespace {

typedef __attribute__((ext_vector_type(8))) short short8v;
typedef __attribute__((ext_vector_type(4))) float f32x4;

constexpr int HEADS = 64;
constexpr size_t HEADQ = 262144;                 // 4096*64 per head
constexpr size_t MATF  = (size_t)HEADS * 262144;

#define MFMA(ACC, A, B) ACC = __builtin_amdgcn_mfma_f32_16x16x32_bf16(A, B, ACC, 0, 0, 0)
#define LD8(arr, row, g8) (*(const short8v*)((arr) + (row) * 72 + (g8) * 8))

__device__ __forceinline__ float rmax16(float m) {
    m = fmaxf(m, __shfl_xor(m, 1));
    m = fmaxf(m, __shfl_xor(m, 2));
    m = fmaxf(m, __shfl_xor(m, 4));
    m = fmaxf(m, __shfl_xor(m, 8));
    return m;
}
__device__ __forceinline__ float rsum16(float s) {
    s += __shfl_xor(s, 1);
    s += __shfl_xor(s, 2);
    s += __shfl_xor(s, 4);
    s += __shfl_xor(s, 8);
    return s;
}

__device__ __forceinline__ void bfsplit(float x, ushort& h, ushort& l) {
    uint u = __float_as_uint(x);
    uint hi = (u + 0x7FFFu + ((u >> 16) & 1u)) & 0xFFFF0000u;
    h = (ushort)(hi >> 16);
    l = (ushort)(__float_as_uint(x - __uint_as_float(hi)) >> 16);
}
__device__ __forceinline__ uint packbf(float x) {
    uint u = __float_as_uint(x);
    uint hi = (u + 0x7FFFu + ((u >> 16) & 1u)) & 0xFFFF0000u;
    return hi | (__float_as_uint(x - __uint_as_float(hi)) >> 16);
}

struct RawU  { uint4 a, b, c, d; };
struct RawF  { float4 a, b, c, d; };
struct Frag16 { short8v h0, h1, l0, l1; };

__device__ __forceinline__ RawU loadU(const uint* __restrict__ p) {
    RawU r;
    r.a = *(const uint4*)(p);      r.b = *(const uint4*)(p + 4);
    r.c = *(const uint4*)(p + 8);  r.d = *(const uint4*)(p + 12);
    return r;
}
__device__ __forceinline__ RawF loadF(const float* __restrict__ p) {
    RawF r;
    r.a = *(const float4*)(p);     r.b = *(const float4*)(p + 4);
    r.c = *(const float4*)(p + 8); r.d = *(const float4*)(p + 12);
    return r;
}
// packed u32 -> split frag (2 ops/elem)
__device__ __forceinline__ Frag16 unpackR(const RawU& r) {
    uint vv[16] = {r.a.x, r.a.y, r.a.z, r.a.w, r.b.x, r.b.y, r.b.z, r.b.w,
                   r.c.x, r.c.y, r.c.z, r.c.w, r.d.x, r.d.y, r.d.z, r.d.w};
    Frag16 f;
    #pragma unroll
    for (int e = 0; e < 8; ++e) {
        f.h0[e] = (short)(vv[e] >> 16);      f.l0[e] = (short)(vv[e] & 0xFFFFu);
        f.h1[e] = (short)(vv[e + 8] >> 16);  f.l1[e] = (short)(vv[e + 8] & 0xFFFFu);
    }
    return f;
}
// f32 -> split frag (6 ops/elem, inputs only)
__device__ __forceinline__ Frag16 splitR(const RawF& r, float s) {
    float vv[16] = {r.a.x*s, r.a.y*s, r.a.z*s, r.a.w*s, r.b.x*s, r.b.y*s, r.b.z*s, r.b.w*s,
                    r.c.x*s, r.c.y*s, r.c.z*s, r.c.w*s, r.d.x*s, r.d.y*s, r.d.z*s, r.d.w*s};
    Frag16 f;
    #pragma unroll
    for (int e = 0; e < 16; ++e) {
        ushort hh, ll; bfsplit(vv[e], hh, ll);
        if (e < 8) { f.h0[e] = (short)hh; f.l0[e] = (short)ll; }
        else       { f.h1[e - 8] = (short)hh; f.l1[e - 8] = (short)ll; }
    }
    return f;
}
__device__ __forceinline__ void store_rows(ushort* H, ushort* L, int r, int c0,
                                           const Frag16& f) {
    *(short8v*)(H + r * 72 + c0)     = f.h0;
    *(short8v*)(H + r * 72 + c0 + 8) = f.h1;
    *(short8v*)(L + r * 72 + c0)     = f.l0;
    *(short8v*)(L + r * 72 + c0 + 8) = f.l1;
}
__device__ __forceinline__ void scatter_tr(ushort* H, ushort* L, int r, int c0,
                                           const Frag16& f) {
    #pragma unroll
    for (int e = 0; e < 8; ++e) {
        H[(c0 + e) * 72 + r] = (ushort)f.h0[e];
        L[(c0 + e) * 72 + r] = (ushort)f.l0[e];
    }
    #pragma unroll
    for (int e = 0; e < 8; ++e) {
        H[(c0 + 8 + e) * 72 + r] = (ushort)f.h1[e];
        L[(c0 + 8 + e) * 72 + r] = (ushort)f.l1[e];
    }
}

__device__ __forceinline__ void mmstep(const ushort* AH, const ushort* AL,
                                       const ushort* BH, const ushort* BL,
                                       int w, int lo4, int hi4, f32x4 acc[4]) {
    #pragma unroll
    for (int ks = 0; ks < 2; ++ks) {
        short8v ah = LD8(AH, 16 * w + lo4, hi4 + 4 * ks);
        short8v al = LD8(AL, 16 * w + lo4, hi4 + 4 * ks);
        #pragma unroll
        for (int t = 0; t < 4; ++t) {
            short8v bh = LD8(BH, 16 * t + lo4, hi4 + 4 * ks);
            short8v bl = LD8(BL, 16 * t + lo4, hi4 + 4 * ks);
            MFMA(acc[t], ah, bh); MFMA(acc[t], ah, bl); MFMA(acc[t], al, bh);
        }
    }
}

// M[h][j][v] = packbf( (1/512) * sum_l Q[h][l*64+j][v] )
__global__ __launch_bounds__(256) void kmean_kernel(const float* __restrict__ Q,
                                                    uint* __restrict__ M) {
    const int wg = blockIdx.x;                      // 1024 WGs
    const int h  = wg >> 4;
    const int j  = ((wg & 15) << 2) + (threadIdx.x >> 6);
    const int v  = threadIdx.x & 63;
    const float* base = Q + (size_t)h * HEADQ + (size_t)j * 64 + v;
    float acc = 0.f;
    #pragma unroll
    for (int l = 0; l < 64; ++l) acc += base[(size_t)l * 4096];
    M[((size_t)h * 64 + j) * 64 + v] = packbf(acc * (1.0f / 512.0f));
}

// One WG per (h, k0..k0+1), grid 2048.
// MM1: beta[j,i]=sum_v G[j,v]K[i,v]; right=softmax_i(beta/tau); alpha[j]=sum r log r
// MM2: Hm[j,v]=sum_i right[j,i]K[i,v];  LAST: Y[j,v]=sum_i right[j,i]V[i,v]
template<int FIRST, int LAST>
__global__ __launch_bounds__(256, 4) void bc_kernel(
    const uint*  __restrict__ Gsrc,   // FIRST ? M[h][j][v] : G[h][j][k][v]
    const float* __restrict__ Kmat,
    const float* __restrict__ Vmat,   // LAST only
    const float* __restrict__ tauIn,  // !FIRST, [h][k][j]
    uint*  __restrict__ HmOut,        // [h][k][j][v] packed
    float* __restrict__ alphaOut,     // [h][j][k]
    uint*  __restrict__ Yout)         // LAST only, [h][k][j][v] packed
{
    __shared__ __align__(16) ushort SM[18432];     // 36864 B -> 4 WG/CU
    ushort* Ah = SM;          ushort* Al = SM + 4608;
    ushort* Bh = SM + 9216;   ushort* Bl = SM + 13824;

    const int wg = blockIdx.x, h = wg >> 5, k0 = (wg & 31) << 1;
    const int tid = threadIdx.x, r = tid & 63, c0 = (tid >> 6) << 4;
    const int w = tid >> 6, lo4 = tid & 15, hi4 = (tid >> 4) & 3;

    const uint*  gB = Gsrc + (FIRST ? ((size_t)h * 64 + r) * 64 + c0
                                    : ((size_t)h * 64 + r) * 4096 + c0);
    const float* kB = Kmat + (size_t)h * HEADQ + (size_t)r * 64 + c0;

    RawU gcur = loadU(FIRST ? gB : gB + (size_t)k0 * 64);
    RawF kcur = loadF(kB + (size_t)k0 * 4096);
    float tcur0, tcur1, tcur2, tcur3;
    if (!FIRST) {
        const float* tp = tauIn + ((size_t)h * 64 + k0) * 64 + 16 * w + 4 * hi4;
        tcur0 = tp[0]; tcur1 = tp[1]; tcur2 = tp[2]; tcur3 = tp[3];
    } else { tcur0 = tcur1 = tcur2 = tcur3 = 1.f; }

    #pragma unroll
    for (int t = 0; t < 2; ++t) {
        const int k = k0 + t;

        store_rows(Ah, Al, r, c0, unpackR(gcur));
        Frag16 fk = splitR(kcur, 1.f);
        store_rows(Bh, Bl, r, c0, fk);

        RawU gnext; RawF knext;
        float tn0 = 1.f, tn1 = 1.f, tn2 = 1.f, tn3 = 1.f;
        if (t == 0) {                       // prefetch next tile (overlaps compute)
            gnext = loadU(FIRST ? gB : gB + (size_t)(k + 1) * 64);
            knext = loadF(kB + (size_t)(k + 1) * 4096);
            if (!FIRST) {
                const float* tp = tauIn + ((size_t)h * 64 + k + 1) * 64 + 16 * w + 4 * hi4;
                tn0 = tp[0]; tn1 = tp[1]; tn2 = tp[2]; tn3 = tp[3];
            }
        }
        __syncthreads();

        f32x4 acc[4] = {};
        mmstep(Ah, Al, Bh, Bl, w, lo4, hi4, acc);      // D[j,i]
        __syncthreads();

        RawF vraw;
        if (LAST)                          // load V under softmax+MM2
            vraw = loadF(Vmat + (size_t)h * HEADQ + (size_t)k * 4096 + r * 64 + c0);

        // softmax over i; right -> A rows; K^T -> B
        const float tvv[4] = {tcur0, tcur1, tcur2, tcur3};
        #pragma unroll
        for (int rr = 0; rr < 4; ++rr) {
            const int j = 16 * w + 4 * hi4 + rr;
            const bool tz = !(tvv[rr] > 1e-8f);
            const float tvi = tz ? 1.f : 1.f / tvv[rr];
            float lg[4];
            #pragma unroll
            for (int tt = 0; tt < 4; ++tt) lg[tt] = acc[tt][rr] * tvi;
            float m = rmax16(fmaxf(fmaxf(lg[0], lg[1]), fmaxf(lg[2], lg[3])));
            float e[4], s = 0.f;
            #pragma unroll
            for (int tt = 0; tt < 4; ++tt) { e[tt] = __expf(lg[tt] - m); s += e[tt]; }
            s = rsum16(s);
            const float inv = 1.f / s;
            float ap = 0.f;
            #pragma unroll
            for (int tt = 0; tt < 4; ++tt) {
                const float rv = tz ? (1.f / 64.f) : e[tt] * inv;
                ap += (rv > 0.f) ? rv * __logf(rv) : 0.f;
                ushort hh, ll; bfsplit(rv, hh, ll);
                Ah[j * 72 + 16 * tt + lo4] = hh;
                Al[j * 72 + 16 * tt + lo4] = ll;
            }
            ap = rsum16(ap);
            if (lo4 == 0) alphaOut[((size_t)h * 64 + j) * 64 + k] = ap;
        }
        scatter_tr(Bh, Bl, r, c0, fk);                 // K^T over dead K rows
        __syncthreads();

        f32x4 acc2[4] = {};
        mmstep(Ah, Al, Bh, Bl, w, lo4, hi4, acc2);     // Hm: A=right, B=K^T
        #pragma unroll
        for (int rr = 0; rr < 4; ++rr) {               // store Hm now (free acc2)
            const int j = 16 * w + 4 * hi4 + rr;
            const size_t ob = ((size_t)h * 64 + k) * 4096 + (size_t)j * 64;
            #pragma unroll
            for (int tt = 0; tt < 4; ++tt)
                HmOut[ob + 16 * tt + lo4] = packbf(acc2[tt][rr]);
        }
        if (LAST) {
            __syncthreads();
            scatter_tr(Bh, Bl, r, c0, splitR(vraw, 1.f)); // V^T over dead K^T
            __syncthreads();
            f32x4 acc3[4] = {};
            mmstep(Ah, Al, Bh, Bl, w, lo4, hi4, acc3); // Y: A=right, B=V^T
            #pragma unroll
            for (int rr = 0; rr < 4; ++rr) {
                const int j = 16 * w + 4 * hi4 + rr;
                const size_t ob = ((size_t)h * 64 + k) * 4096 + (size_t)j * 64;
                #pragma unroll
                for (int tt = 0; tt < 4; ++tt)
                    Yout[ob + 16 * tt + lo4] = packbf(acc3[tt][rr]);
            }
        }
        __syncthreads();                               // LDS free for next tile

        gcur = gnext; kcur = knext;
        tcur0 = tn0; tcur1 = tn1; tcur2 = tn2; tcur3 = tn3;
    }
}

// One WG per (h, j0..j0+1), grid 2048.
// MM1: beta2[l,k]=sum_v q[l,v]Hm[k,v]; left=softmax_k(beta2-alpha[k])
// !LAST: G[k,v]=sum_l left[l,k]q[l,v] (packed); tau[k] via ones-MFMA
//  LAST: Z[l,v]=sum_k left[l,k]Y[k,v] (f32)
template<int LAST>
__global__ __launch_bounds__(256, 4) void da_kernel(
    const float* __restrict__ Q,
    const uint*  __restrict__ HmIn,   // [h][k][j][v] packed
    const float* __restrict__ alphaIn,// [h][j][k]
    const uint*  __restrict__ Yin,    // LAST only, packed
    uint*  __restrict__ Gout,         // !LAST, [h][j][k][v] packed
    float* __restrict__ tauOut,       // !LAST, [h][k][j]
    float* __restrict__ Zout)         // LAST
{
    __shared__ __align__(16) ushort SM[18432];
    ushort* Ah = SM;          ushort* Al = SM + 4608;
    ushort* Bh = SM + 9216;   ushort* Bl = SM + 13824;

    const int wg = blockIdx.x, h = wg >> 5, j0 = (wg & 31) << 1;
    const int tid = threadIdx.x, r = tid & 63, c0 = (tid >> 6) << 4;
    const int w = tid >> 6, lo4 = tid & 15, hi4 = (tid >> 4) & 3;

    const float* qB = Q    + (size_t)h * HEADQ + (size_t)r * 4096 + c0;
    const uint*  hB = HmIn + ((size_t)h * 64 + r) * 4096 + c0;

    RawF qcur = loadF(qB + (size_t)j0 * 64);
    RawU hcur = loadU(hB + (size_t)j0 * 64);
    float acur0, acur1, acur2, acur3;
    {
        const float* ap = alphaIn + ((size_t)h * 64 + j0) * 64;
        acur0 = ap[lo4]; acur1 = ap[16 + lo4]; acur2 = ap[32 + lo4]; acur3 = ap[48 + lo4];
    }

    #pragma unroll
    for (int t = 0; t < 2; ++t) {
        const int j = j0 + t;

        Frag16 fq = splitR(qcur, 0.125f);
        store_rows(Ah, Al, r, c0, fq);
        store_rows(Bh, Bl, r, c0, unpackR(hcur));

        RawF qnext; RawU hnext;
        float an0 = 0.f, an1 = 0.f, an2 = 0.f, an3 = 0.f;
        if (t == 0) {                       // prefetch next tile
            qnext = loadF(qB + (size_t)(j + 1) * 64);
            hnext = loadU(hB + (size_t)(j + 1) * 64);
            const float* ap = alphaIn + ((size_t)h * 64 + j + 1) * 64;
            an0 = ap[lo4]; an1 = ap[16 + lo4]; an2 = ap[32 + lo4]; an3 = ap[48 + lo4];
        }
        __syncthreads();

        f32x4 acc[4] = {};
        mmstep(Ah, Al, Bh, Bl, w, lo4, hi4, acc);      // D[l,k]
        __syncthreads();

        RawU yraw;
        if (LAST)                          // load Y under softmax
            yraw = loadU(Yin + ((size_t)h * 64 + r) * 4096 + (size_t)j * 64 + c0);

        // left = softmax over k; left(^T) -> B; q^T / Y^T -> A
        const float av[4] = {acur0, acur1, acur2, acur3};
        #pragma unroll
        for (int rr = 0; rr < 4; ++rr) {
            const int l = 16 * w + 4 * hi4 + rr;
            float lg[4];
            #pragma unroll
            for (int tt = 0; tt < 4; ++tt) lg[tt] = acc[tt][rr] - av[tt];
            float m = rmax16(fmaxf(fmaxf(lg[0], lg[1]), fmaxf(lg[2], lg[3])));
            float e[4], s = 0.f;
            #pragma unroll
            for (int tt = 0; tt < 4; ++tt) { e[tt] = __expf(lg[tt] - m); s += e[tt]; }
            s = rsum16(s);
            const float inv = 1.f / s;
            #pragma unroll
            for (int tt = 0; tt < 4; ++tt) {
                const float lv = e[tt] * inv;
                ushort hh, ll; bfsplit(lv, hh, ll);
                if (!LAST) { Bh[(16 * tt + lo4) * 72 + l] = hh; Bl[(16 * tt + lo4) * 72 + l] = ll; }
                else       { Bh[l * 72 + 16 * tt + lo4] = hh; Bl[l * 72 + 16 * tt + lo4] = ll; }
            }
        }
        if (!LAST) scatter_tr(Ah, Al, r, c0, fq);      // q^T over dead q rows
        else       scatter_tr(Ah, Al, r, c0, unpackR(yraw)); // Y^T over dead q rows
        __syncthreads();

        if (!LAST) {
            f32x4 acc2[4] = {};
            f32x4 tacc = {};
            short8v onesb;
            #pragma unroll
            for (int e2 = 0; e2 < 8; ++e2) onesb[e2] = (lo4 == 0) ? (short)0x3F80 : (short)0;
            #pragma unroll
            for (int ks = 0; ks < 2; ++ks) {
                short8v ah = LD8(Bh, 16 * w + lo4, hi4 + 4 * ks);   // left^T rows (k)
                short8v al = LD8(Bl, 16 * w + lo4, hi4 + 4 * ks);
                MFMA(tacc, ah, onesb); MFMA(tacc, al, onesb);
                #pragma unroll
                for (int tt = 0; tt < 4; ++tt) {
                    short8v bh = LD8(Ah, 16 * tt + lo4, hi4 + 4 * ks); // q^T rows (v)
                    short8v bl = LD8(Al, 16 * tt + lo4, hi4 + 4 * ks);
                    MFMA(acc2[tt], ah, bh); MFMA(acc2[tt], ah, bl); MFMA(acc2[tt], al, bh);
                }
            }
            #pragma unroll
            for (int rr = 0; rr < 4; ++rr) {           // direct packed stores
                const int kq = 16 * w + 4 * hi4 + rr;
                if (lo4 == 0) tauOut[((size_t)h * 64 + kq) * 64 + j] = tacc[rr];
                const size_t gb = ((size_t)h * 64 + j) * 4096 + (size_t)kq * 64;
                #pragma unroll
                for (int tt = 0; tt < 4; ++tt) Gout[gb + 16 * tt + lo4] = packbf(acc2[tt][rr]);
            }
        } else {
            f32x4 acc2[4] = {};
            #pragma unroll
            for (int ks = 0; ks < 2; ++ks) {
                short8v ah = LD8(Bh, 16 * w + lo4, hi4 + 4 * ks);   // left rows (l)
                short8v al = LD8(Bl, 16 * w + lo4, hi4 + 4 * ks);
                #pragma unroll
                for (int tt = 0; tt < 4; ++tt) {
                    short8v bh = LD8(Ah, 16 * tt + lo4, hi4 + 4 * ks); // Y^T rows (v)
                    short8v bl = LD8(Al, 16 * tt + lo4, hi4 + 4 * ks);
                    MFMA(acc2[tt], ah, bh); MFMA(acc2[tt], ah, bl); MFMA(acc2[tt], al, bh);
                }
            }
            #pragma unroll
            for (int rr = 0; rr < 4; ++rr) {           // direct f32 stores (64B/group)
                const int l = 16 * w + 4 * hi4 + rr;
                const size_t zb = (size_t)h * HEADQ + (size_t)l * 4096 + (size_t)j * 64;
                #pragma unroll
                for (int tt = 0; tt < 4; ++tt) Zout[zb + 16 * tt + lo4] = acc2[tt][rr];
            }
        }
        __syncthreads();                               // LDS free for next tile

        qcur = qnext; hcur = hnext;
        acur0 = an0; acur1 = an1; acur2 = an2; acur3 = an3;
    }
}

} // namespace

extern "C" void kernel_launch(void* const* d_in, const int* in_sizes, int n_in,
                              void* d_out, int out_size, void* d_ws, size_t ws_size,
                              hipStream_t stream) {
    const float* Q = (const float*)d_in[0];
    const float* K = (const float*)d_in[1];
    const float* V = (const float*)d_in[2];
    float* out = (float*)d_out;

    char* ws = (char*)d_ws;
    const size_t MB = 1024 * 1024;
    uint*  G   = (uint*)(ws);                   // 64 MiB packed (fallback: z staging)
    uint*  Hm  = (uint*)(ws + 64 * MB);         // 64 MiB packed
    uint*  M   = (uint*)(ws + 128 * MB);        //  1 MiB packed
    float* al  = (float*)(ws + 129 * MB);       //  1 MiB
    float* tau = (float*)(ws + 130 * MB);       //  1 MiB

    const bool bigws = ws_size >= (size_t)195 * MB;
    uint*  Ybuf = bigws ? (uint*)(ws + 131 * MB) : (uint*)out;  // packed Y staging
    float* Zdst = bigws ? out : (float*)G;

    dim3 blk(256), grid(2048);

    kmean_kernel<<<dim3(1024), blk, 0, stream>>>(Q, M);
    bc_kernel<1, 0><<<grid, blk, 0, stream>>>(M, K, nullptr, nullptr, Hm, al, nullptr);
    da_kernel<0>   <<<grid, blk, 0, stream>>>(Q, Hm, al, nullptr, G, tau, nullptr);
    bc_kernel<0, 0><<<grid, blk, 0, stream>>>(G, K, nullptr, tau, Hm, al, nullptr);
    da_kernel<0>   <<<grid, blk, 0, stream>>>(Q, Hm, al, nullptr, G, tau, nullptr);
    bc_kernel<0, 1><<<grid, blk, 0, stream>>>(G, K, V, tau, Hm, al, Ybuf);
    da_kernel<1>   <<<grid, blk, 0, stream>>>(Q, Hm, al, Ybuf, nullptr, nullptr, Zdst);
    if (!bigws)
        hipMemcpyAsync(d_out, Zdst, MATF * sizeof(float), hipMemcpyDeviceToDevice, stream);
}

// Round 9
// 310.579 us; speedup vs baseline: 1.1435x; 1.1435x over previous
//
#include <hip/hip_runtime.h>

// SOBA-Monarch, B*H=64 heads, S=4096, D=64, nb=bs=64, pad=0, 3 steps.
// Round 9 = R4 structure (grid 4096, 1 tile/WG, pad-72 LDS, (256,4)) +
//   direct stores + packed-u32 intermediates (R7) + R4 alpha/tau orientation +
//   SWAPPED-OPERAND MM1: beta computed transposed so softmax is in-lane
//   (16 values/lane, 2 shfls per reduce instead of 4-shfl butterflies).
// Layouts: G [h][j][k][v] u32 | Hm,Y [h][k][j][v] u32 | M [h][j][v] u32
//          alpha [h][j][k] f32 | tau [h][k][j] f32

namespace {

typedef __attribute__((ext_vector_type(8))) short short8v;
typedef __attribute__((ext_vector_type(4))) float f32x4;

constexpr int HEADS = 64;
constexpr size_t HEADQ = 262144;                 // 4096*64 per head
constexpr size_t MATF  = (size_t)HEADS * 262144;

#define MFMA(ACC, A, B) ACC = __builtin_amdgcn_mfma_f32_16x16x32_bf16(A, B, ACC, 0, 0, 0)
#define LD8(arr, row, g8) (*(const short8v*)((arr) + (row) * 72 + (g8) * 8))

__device__ __forceinline__ void bfsplit(float x, ushort& h, ushort& l) {
    uint u = __float_as_uint(x);
    uint hi = (u + 0x7FFFu + ((u >> 16) & 1u)) & 0xFFFF0000u;
    h = (ushort)(hi >> 16);
    l = (ushort)(__float_as_uint(x - __uint_as_float(hi)) >> 16);
}
__device__ __forceinline__ uint packbf(float x) {
    uint u = __float_as_uint(x);
    uint hi = (u + 0x7FFFu + ((u >> 16) & 1u)) & 0xFFFF0000u;
    return hi | (__float_as_uint(x - __uint_as_float(hi)) >> 16);
}

struct Frag16 { short8v h0, h1, l0, l1; };

// f32 global (16 elems) -> split regs
__device__ __forceinline__ Frag16 split_load(const float* __restrict__ p, float s) {
    Frag16 f;
    #pragma unroll
    for (int q = 0; q < 4; ++q) {
        float4 a = *(const float4*)(p + 4 * q);
        float v[4] = {a.x * s, a.y * s, a.z * s, a.w * s};
        #pragma unroll
        for (int e = 0; e < 4; ++e) {
            ushort hh, ll; bfsplit(v[e], hh, ll);
            const int i = 4 * q + e;
            if (i < 8) { f.h0[i] = (short)hh; f.l0[i] = (short)ll; }
            else       { f.h1[i - 8] = (short)hh; f.l1[i - 8] = (short)ll; }
        }
    }
    return f;
}
// packed-u32 global -> split regs (2 ops/elem)
__device__ __forceinline__ Frag16 unpack_load(const uint* __restrict__ p) {
    Frag16 f;
    #pragma unroll
    for (int q = 0; q < 2; ++q) {
        uint4 a = *(const uint4*)(p + 8 * q);
        uint4 b = *(const uint4*)(p + 8 * q + 4);
        uint vv[8] = {a.x, a.y, a.z, a.w, b.x, b.y, b.z, b.w};
        short8v h, l;
        #pragma unroll
        for (int e = 0; e < 8; ++e) {
            h[e] = (short)(vv[e] >> 16);
            l[e] = (short)(vv[e] & 0xFFFFu);
        }
        if (q == 0) { f.h0 = h; f.l0 = l; } else { f.h1 = h; f.l1 = l; }
    }
    return f;
}
__device__ __forceinline__ void store_rows(ushort* H, ushort* L, int r, int c0,
                                           const Frag16& f) {
    *(short8v*)(H + r * 72 + c0)     = f.h0;
    *(short8v*)(H + r * 72 + c0 + 8) = f.h1;
    *(short8v*)(L + r * 72 + c0)     = f.l0;
    *(short8v*)(L + r * 72 + c0 + 8) = f.l1;
}
__device__ __forceinline__ void scatter_tr(ushort* H, ushort* L, int r, int c0,
                                           const Frag16& f) {
    #pragma unroll
    for (int e = 0; e < 8; ++e) {
        H[(c0 + e) * 72 + r] = (ushort)f.h0[e];
        L[(c0 + e) * 72 + r] = (ushort)f.l0[e];
    }
    #pragma unroll
    for (int e = 0; e < 8; ++e) {
        H[(c0 + 8 + e) * 72 + r] = (ushort)f.h1[e];
        L[(c0 + 8 + e) * 72 + r] = (ushort)f.l1[e];
    }
}

__device__ __forceinline__ void mmstep(const ushort* AH, const ushort* AL,
                                       const ushort* BH, const ushort* BL,
                                       int w, int lo4, int hi4, f32x4 acc[4]) {
    #pragma unroll
    for (int ks = 0; ks < 2; ++ks) {
        short8v ah = LD8(AH, 16 * w + lo4, hi4 + 4 * ks);
        short8v al = LD8(AL, 16 * w + lo4, hi4 + 4 * ks);
        #pragma unroll
        for (int t = 0; t < 4; ++t) {
            short8v bh = LD8(BH, 16 * t + lo4, hi4 + 4 * ks);
            short8v bl = LD8(BL, 16 * t + lo4, hi4 + 4 * ks);
            MFMA(acc[t], ah, bh); MFMA(acc[t], ah, bl); MFMA(acc[t], al, bh);
        }
    }
}
// swapped: acc[m] = A-strip m (from Bregion) x B-strip w (from Aregion)
__device__ __forceinline__ void mmstep_swap(const ushort* AH, const ushort* AL,
                                            const ushort* BH, const ushort* BL,
                                            int w, int lo4, int hi4, f32x4 acc[4]) {
    #pragma unroll
    for (int ks = 0; ks < 2; ++ks) {
        short8v bh = LD8(AH, 16 * w + lo4, hi4 + 4 * ks);   // B operand (j/l strip w)
        short8v bl = LD8(AL, 16 * w + lo4, hi4 + 4 * ks);
        #pragma unroll
        for (int m = 0; m < 4; ++m) {
            short8v ah = LD8(BH, 16 * m + lo4, hi4 + 4 * ks); // A operand (i/k strip m)
            short8v al = LD8(BL, 16 * m + lo4, hi4 + 4 * ks);
            MFMA(acc[m], ah, bh); MFMA(acc[m], ah, bl); MFMA(acc[m], al, bh);
        }
    }
}

// in-lane 16-value max / sum helpers
__device__ __forceinline__ float max16(const float* x) {
    float a = fmaxf(fmaxf(x[0], x[1]), fmaxf(x[2], x[3]));
    float b = fmaxf(fmaxf(x[4], x[5]), fmaxf(x[6], x[7]));
    float c = fmaxf(fmaxf(x[8], x[9]), fmaxf(x[10], x[11]));
    float d = fmaxf(fmaxf(x[12], x[13]), fmaxf(x[14], x[15]));
    return fmaxf(fmaxf(a, b), fmaxf(c, d));
}
__device__ __forceinline__ float sum16(const float* x) {
    float a = (x[0] + x[1]) + (x[2] + x[3]);
    float b = (x[4] + x[5]) + (x[6] + x[7]);
    float c = (x[8] + x[9]) + (x[10] + x[11]);
    float d = (x[12] + x[13]) + (x[14] + x[15]);
    return (a + b) + (c + d);
}

// M[h][j][v] = packbf( (1/512) * sum_l Q[h][l*64+j][v] )
__global__ __launch_bounds__(256) void kmean_kernel(const float* __restrict__ Q,
                                                    uint* __restrict__ M) {
    const int wg = blockIdx.x;                      // 1024 WGs
    const int h  = wg >> 4;
    const int j  = ((wg & 15) << 2) + (threadIdx.x >> 6);
    const int v  = threadIdx.x & 63;
    const float* base = Q + (size_t)h * HEADQ + (size_t)j * 64 + v;
    float acc = 0.f;
    #pragma unroll
    for (int l = 0; l < 64; ++l) acc += base[(size_t)l * 4096];
    M[((size_t)h * 64 + j) * 64 + v] = packbf(acc * (1.0f / 512.0f));
}

// One WG (256T) per (h,k).
// MM1 (swapped): beta^T[i,j]; softmax over i is in-lane; alpha[j]=sum r log r
// MM2: Hm[j,v]=sum_i right[j,i]K[i,v];  LAST: Y[j,v]=sum_i right[j,i]V[i,v]
template<int FIRST, int LAST>
__global__ __launch_bounds__(256, 4) void bc_kernel(
    const uint*  __restrict__ Gsrc,   // FIRST ? M[h][j][v] : G[h][j][k][v]
    const float* __restrict__ Kmat,
    const float* __restrict__ Vmat,   // LAST only
    const float* __restrict__ tauIn,  // !FIRST, [h][k][j]
    uint*  __restrict__ HmOut,        // [h][k][j][v] packed
    float* __restrict__ alphaOut,     // [h][j][k]
    uint*  __restrict__ Yout)         // LAST only, [h][k][j][v] packed
{
    __shared__ __align__(16) ushort SM[18432];     // 36864 B -> 4 WG/CU
    ushort* Ah = SM;          ushort* Al = SM + 4608;   // G rows -> right rows
    ushort* Bh = SM + 9216;   ushort* Bl = SM + 13824;  // K rows -> K^T -> V^T

    const int wg = blockIdx.x, h = wg >> 6, k = wg & 63;
    const int tid = threadIdx.x, r = tid & 63, c0 = (tid >> 6) << 4;
    const int w = tid >> 6, lo4 = tid & 15, hi4 = (tid >> 4) & 3;

    { // stage G rows -> A (cheap unpack)
        const uint* gp = FIRST ? Gsrc + ((size_t)h * 64 + r) * 64 + c0
                               : Gsrc + ((size_t)h * 64 + r) * 4096 + (size_t)k * 64 + c0;
        store_rows(Ah, Al, r, c0, unpack_load(gp));
    }
    // stage K rows -> B, keep regs for K^T scatter
    Frag16 fk = split_load(Kmat + (size_t)h * HEADQ + (size_t)k * 4096 + r * 64 + c0, 1.f);
    store_rows(Bh, Bl, r, c0, fk);
    Frag16 fv;
    if (LAST)
        fv = split_load(Vmat + (size_t)h * HEADQ + (size_t)k * 4096 + r * 64 + c0, 1.f);
    // tau: one scalar per lane (j = 16w + lo4), contiguous read
    float tv = 1.f;
    if (!FIRST) tv = tauIn[((size_t)h * 64 + k) * 64 + 16 * w + lo4];
    __syncthreads();

    // MM1 swapped: acc[m][reg] = beta[i=16m+4hi4+reg][j=16w+lo4]
    f32x4 acc[4] = {};
    mmstep_swap(Ah, Al, Bh, Bl, w, lo4, hi4, acc);
    __syncthreads();

    // softmax over i: in-lane 16 + shfl_xor(16,32); per-lane j
    {
        const int j = 16 * w + lo4;
        const bool tz = !(tv > 1e-8f);
        const float tvi = tz ? 1.f : 1.f / tv;
        float x[16];
        #pragma unroll
        for (int m = 0; m < 4; ++m)
            #pragma unroll
            for (int rg = 0; rg < 4; ++rg) x[4 * m + rg] = acc[m][rg] * tvi;
        float mx = max16(x);
        mx = fmaxf(mx, __shfl_xor(mx, 16));
        mx = fmaxf(mx, __shfl_xor(mx, 32));
        #pragma unroll
        for (int e = 0; e < 16; ++e) x[e] = __expf(x[e] - mx);
        float s = sum16(x);
        s += __shfl_xor(s, 16);
        s += __shfl_xor(s, 32);
        const float inv = 1.f / s;
        float ap = 0.f;
        #pragma unroll
        for (int m = 0; m < 4; ++m) {
            #pragma unroll
            for (int rg = 0; rg < 4; ++rg) {
                const float rv = tz ? (1.f / 64.f) : x[4 * m + rg] * inv;
                ap += (rv > 0.f) ? rv * __logf(rv) : 0.f;
                ushort hh, ll; bfsplit(rv, hh, ll);
                const int i = 16 * m + 4 * hi4 + rg;
                Ah[j * 72 + i] = hh;                 // right rows [j][i]
                Al[j * 72 + i] = ll;
            }
        }
        ap += __shfl_xor(ap, 16);
        ap += __shfl_xor(ap, 32);
        if (hi4 == 0) alphaOut[((size_t)h * 64 + j) * 64 + k] = ap;
    }
    scatter_tr(Bh, Bl, r, c0, fk);                 // K^T over dead K rows
    __syncthreads();

    f32x4 acc2[4] = {};
    mmstep(Ah, Al, Bh, Bl, w, lo4, hi4, acc2);     // Hm: A=right rows, B=K^T
    #pragma unroll
    for (int rr = 0; rr < 4; ++rr) {               // direct packed stores
        const int j = 16 * w + 4 * hi4 + rr;
        const size_t ob = ((size_t)h * 64 + k) * 4096 + (size_t)j * 64;
        #pragma unroll
        for (int t = 0; t < 4; ++t)
            HmOut[ob + 16 * t + lo4] = packbf(acc2[t][rr]);
    }
    if (LAST) {
        __syncthreads();
        scatter_tr(Bh, Bl, r, c0, fv);             // V^T over dead K^T
        __syncthreads();
        f32x4 acc3[4] = {};
        mmstep(Ah, Al, Bh, Bl, w, lo4, hi4, acc3); // Y: A=right, B=V^T
        #pragma unroll
        for (int rr = 0; rr < 4; ++rr) {
            const int j = 16 * w + 4 * hi4 + rr;
            const size_t ob = ((size_t)h * 64 + k) * 4096 + (size_t)j * 64;
            #pragma unroll
            for (int t = 0; t < 4; ++t)
                Yout[ob + 16 * t + lo4] = packbf(acc3[t][rr]);
        }
    }
}

// One WG per (h,j).
// MM1 (swapped): beta2^T[k,l]; left = softmax over k (in-lane)
// !LAST: G[k,v]=sum_l left[l,k]q[l,v] (packed); tau[k] via ones-MFMA
//  LAST: Z[l,v]=sum_k left[l,k]Y[k,v] (f32)
template<int LAST>
__global__ __launch_bounds__(256, 4) void da_kernel(
    const float* __restrict__ Q,
    const uint*  __restrict__ HmIn,   // [h][k][j][v] packed
    const float* __restrict__ alphaIn,// [h][j][k]
    const uint*  __restrict__ Yin,    // LAST only, packed
    uint*  __restrict__ Gout,         // !LAST, [h][j][k][v] packed
    float* __restrict__ tauOut,       // !LAST, [h][k][j]
    float* __restrict__ Zout)         // LAST
{
    __shared__ __align__(16) ushort SM[18432];
    ushort* Ah = SM;          ushort* Al = SM + 4608;   // q rows -> q^T / Y^T
    ushort* Bh = SM + 9216;   ushort* Bl = SM + 13824;  // Hm rows -> left

    const int wg = blockIdx.x, h = wg >> 6, j = wg & 63;
    const int tid = threadIdx.x, r = tid & 63, c0 = (tid >> 6) << 4;
    const int w = tid >> 6, lo4 = tid & 15, hi4 = (tid >> 4) & 3;

    // stage q (x0.125) -> A, keep regs for q^T
    Frag16 fq = split_load(Q + (size_t)h * HEADQ + (size_t)r * 4096 + (size_t)j * 64 + c0,
                           0.125f);
    store_rows(Ah, Al, r, c0, fq);
    { // stage Hm rows -> B (cheap unpack)
        store_rows(Bh, Bl, r, c0,
                   unpack_load(HmIn + ((size_t)h * 64 + r) * 4096 + (size_t)j * 64 + c0));
    }
    Frag16 fy;
    if (LAST)
        fy = unpack_load(Yin + ((size_t)h * 64 + r) * 4096 + (size_t)j * 64 + c0);
    // alpha[k] per in-lane k = 16m + 4hi4 + rg (contiguous 256-B hot region)
    float av[16];
    {
        const float* ap0 = alphaIn + ((size_t)h * 64 + j) * 64 + 4 * hi4;
        #pragma unroll
        for (int m = 0; m < 4; ++m)
            #pragma unroll
            for (int rg = 0; rg < 4; ++rg) av[4 * m + rg] = ap0[16 * m + rg];
    }
    __syncthreads();

    // MM1 swapped: acc[m][rg] = beta2[k=16m+4hi4+rg][l=16w+lo4]
    f32x4 acc[4] = {};
    mmstep_swap(Ah, Al, Bh, Bl, w, lo4, hi4, acc);
    __syncthreads();

    // left = softmax over k: in-lane 16 + shfl_xor(16,32); per-lane l
    {
        const int l = 16 * w + lo4;
        float x[16];
        #pragma unroll
        for (int m = 0; m < 4; ++m)
            #pragma unroll
            for (int rg = 0; rg < 4; ++rg) x[4 * m + rg] = acc[m][rg] - av[4 * m + rg];
        float mx = max16(x);
        mx = fmaxf(mx, __shfl_xor(mx, 16));
        mx = fmaxf(mx, __shfl_xor(mx, 32));
        #pragma unroll
        for (int e = 0; e < 16; ++e) x[e] = __expf(x[e] - mx);
        float s = sum16(x);
        s += __shfl_xor(s, 16);
        s += __shfl_xor(s, 32);
        const float inv = 1.f / s;
        #pragma unroll
        for (int m = 0; m < 4; ++m) {
            #pragma unroll
            for (int rg = 0; rg < 4; ++rg) {
                const float lv = x[4 * m + rg] * inv;
                ushort hh, ll; bfsplit(lv, hh, ll);
                const int kk = 16 * m + 4 * hi4 + rg;
                if (!LAST) { Bh[kk * 72 + l] = hh; Bl[kk * 72 + l] = ll; }  // left^T [k][l]
                else       { Bh[l * 72 + kk] = hh; Bl[l * 72 + kk] = ll; }  // left [l][k]
            }
        }
    }
    if (!LAST) scatter_tr(Ah, Al, r, c0, fq);      // q^T over dead q rows
    else       scatter_tr(Ah, Al, r, c0, fy);      // Y^T over dead q rows
    __syncthreads();

    if (!LAST) {
        f32x4 acc2[4] = {};
        f32x4 tacc = {};
        short8v onesb;
        #pragma unroll
        for (int e2 = 0; e2 < 8; ++e2) onesb[e2] = (lo4 == 0) ? (short)0x3F80 : (short)0;
        #pragma unroll
        for (int ks = 0; ks < 2; ++ks) {
            short8v ah = LD8(Bh, 16 * w + lo4, hi4 + 4 * ks);   // left^T rows (k)
            short8v al = LD8(Bl, 16 * w + lo4, hi4 + 4 * ks);
            MFMA(tacc, ah, onesb); MFMA(tacc, al, onesb);
            #pragma unroll
            for (int t = 0; t < 4; ++t) {
                short8v bh = LD8(Ah, 16 * t + lo4, hi4 + 4 * ks); // q^T rows (v)
                short8v bl = LD8(Al, 16 * t + lo4, hi4 + 4 * ks);
                MFMA(acc2[t], ah, bh); MFMA(acc2[t], ah, bl); MFMA(acc2[t], al, bh);
            }
        }
        #pragma unroll
        for (int rr = 0; rr < 4; ++rr) {           // direct packed stores
            const int kq = 16 * w + 4 * hi4 + rr;
            if (lo4 == 0) tauOut[((size_t)h * 64 + kq) * 64 + j] = tacc[rr];
            const size_t gb = ((size_t)h * 64 + j) * 4096 + (size_t)kq * 64;
            #pragma unroll
            for (int t = 0; t < 4; ++t) Gout[gb + 16 * t + lo4] = packbf(acc2[t][rr]);
        }
    } else {
        f32x4 acc2[4] = {};
        #pragma unroll
        for (int ks = 0; ks < 2; ++ks) {
            short8v ah = LD8(Bh, 16 * w + lo4, hi4 + 4 * ks);   // left rows (l)
            short8v al = LD8(Bl, 16 * w + lo4, hi4 + 4 * ks);
            #pragma unroll
            for (int t = 0; t < 4; ++t) {
                short8v bh = LD8(Ah, 16 * t + lo4, hi4 + 4 * ks); // Y^T rows (v)
                short8v bl = LD8(Al, 16 * t + lo4, hi4 + 4 * ks);
                MFMA(acc2[t], ah, bh); MFMA(acc2[t], ah, bl); MFMA(acc2[t], al, bh);
            }
        }
        #pragma unroll
        for (int rr = 0; rr < 4; ++rr) {           // direct f32 stores (64B/group)
            const int l = 16 * w + 4 * hi4 + rr;
            const size_t zb = (size_t)h * HEADQ + (size_t)l * 4096 + (size_t)j * 64;
            #pragma unroll
            for (int t = 0; t < 4; ++t) Zout[zb + 16 * t + lo4] = acc2[t][rr];
        }
    }
}

} // namespace

extern "C" void kernel_launch(void* const* d_in, const int* in_sizes, int n_in,
                              void* d_out, int out_size, void* d_ws, size_t ws_size,
                              hipStream_t stream) {
    const float* Q = (const float*)d_in[0];
    const float* K = (const float*)d_in[1];
    const float* V = (const float*)d_in[2];
    float* out = (float*)d_out;

    char* ws = (char*)d_ws;
    const size_t MB = 1024 * 1024;
    uint*  G   = (uint*)(ws);                   // 64 MiB packed (fallback: z staging)
    uint*  Hm  = (uint*)(ws + 64 * MB);         // 64 MiB packed
    uint*  M   = (uint*)(ws + 128 * MB);        //  1 MiB packed
    float* al  = (float*)(ws + 129 * MB);       //  1 MiB
    float* tau = (float*)(ws + 130 * MB);       //  1 MiB

    const bool bigws = ws_size >= (size_t)195 * MB;
    uint*  Ybuf = bigws ? (uint*)(ws + 131 * MB) : (uint*)out;  // packed Y staging
    float* Zdst = bigws ? out : (float*)G;

    dim3 blk(256), grid(HEADS * 64);

    kmean_kernel<<<dim3(1024), blk, 0, stream>>>(Q, M);
    bc_kernel<1, 0><<<grid, blk, 0, stream>>>(M, K, nullptr, nullptr, Hm, al, nullptr);
    da_kernel<0>   <<<grid, blk, 0, stream>>>(Q, Hm, al, nullptr, G, tau, nullptr);
    bc_kernel<0, 0><<<grid, blk, 0, stream>>>(G, K, nullptr, tau, Hm, al, nullptr);
    da_kernel<0>   <<<grid, blk, 0, stream>>>(Q, Hm, al, nullptr, G, tau, nullptr);
    bc_kernel<0, 1><<<grid, blk, 0, stream>>>(G, K, V, tau, Hm, al, Ybuf);
    da_kernel<1>   <<<grid, blk, 0, stream>>>(Q, Hm, al, Ybuf, nullptr, nullptr, Zdst);
    if (!bigws)
        hipMemcpyAsync(d_out, Zdst, MATF * sizeof(float), hipMemcpyDeviceToDevice, stream);
}